// Round 3
// baseline (186.357 us; speedup 1.0000x reference)
//
#include <hip/hip_runtime.h>
#include <math.h>

namespace {
constexpr int kB = 2, kN = 2048, kDim = 256, kH = 8, kDH = 32;
constexpr int kBH = kB * kH;
constexpr long kPlane = (long)kBH * kN * kDH;  // 1,048,576 elems per tensor
// DH^-0.5 / ln2 folded into stored q so softmax weight = exp2(score)
constexpr float kQScaleL2 = 0.25506852552f;
}

typedef unsigned short u16;
typedef short short8 __attribute__((ext_vector_type(8)));
typedef short short4v __attribute__((ext_vector_type(4)));
typedef float floatx16 __attribute__((ext_vector_type(16)));
#define MFMA_BF16(a, b, c) __builtin_amdgcn_mfma_f32_32x32x16_bf16(a, b, c, 0, 0, 0)

__device__ inline u16 bf16b(float x) {
    union { float f; unsigned u; } c; c.f = x;
    unsigned r = c.u + 0x7FFFu + ((c.u >> 16) & 1u);
    return (u16)(r >> 16);
}
__device__ inline unsigned pack2(float x, float y) {
    return (unsigned)bf16b(x) | ((unsigned)bf16b(y) << 16);
}
// truncating bf16 pack of two floats via one v_perm_b32
__device__ inline unsigned packtr(float lo, float hi) {
    return __builtin_amdgcn_perm(__float_as_uint(hi), __float_as_uint(lo), 0x07060302u);
}
// fused exp2 + truncating bf16 pack of 8 consecutive S entries
__device__ inline short8 mk8exp(const floatx16& S, int b) {
    union { unsigned u[4]; short8 s; } c;
    #pragma unroll
    for (int j = 0; j < 4; ++j)
        c.u[j] = packtr(__builtin_amdgcn_exp2f(S[b + 2 * j]),
                        __builtin_amdgcn_exp2f(S[b + 2 * j + 1]));
    return c.s;
}

// ---------------------------------------------------------------------------
// Build doubled/transposed bf16 weight matrices (unchanged).
// ---------------------------------------------------------------------------
__global__ __launch_bounds__(256, 2) void prep_w(
    const float* __restrict__ wq_r, const float* __restrict__ wq_i,
    const float* __restrict__ wkv_r, const float* __restrict__ wkv_i,
    const float* __restrict__ wo_r, const float* __restrict__ wo_i,
    u16* __restrict__ Wbig, u16* __restrict__ WoT)
{
    const long base = ((long)blockIdx.x * 256 + threadIdx.x) * 4;
    if (base < 786432) {
        const int c = (int)(base >> 9);
        const int k = (int)(base & 511);
        const int g = c >> 8, d = c & 255;
        const bool hi = k >= 256;
        const int k2 = hi ? k - 256 : k;
        const float* src;
        float sgn = 1.f;
        int col, stride;
        if (g < 2) {
            stride = 256; col = d;
            if (g == 0) { src = hi ? wq_i : wq_r; if (hi) sgn = -1.f; }
            else        { src = hi ? wq_r : wq_i; }
            sgn *= kQScaleL2;
        } else {
            stride = 512;
            col = (g >= 4) ? d + 256 : d;
            if ((g & 1) == 0) { src = hi ? wkv_i : wkv_r; if (hi) sgn = -1.f; }
            else              { src = hi ? wkv_r : wkv_i; }
        }
        short4v v;
        #pragma unroll
        for (int j = 0; j < 4; ++j)
            v[j] = (short)bf16b(src[(long)(k2 + j) * stride + col] * sgn);
        *(short4v*)(Wbig + base) = v;
    } else {
        const long o = base - 786432;
        const int c = (int)(o >> 9);
        const int k = (int)(o & 511);
        const bool hi = k >= 256;
        const int k2 = hi ? k - 256 : k;
        const float* src;
        float sgn = 1.f;
        int col;
        if (c < 256) { col = c;       src = hi ? wo_i : wo_r; if (hi) sgn = -1.f; }
        else         { col = c - 256; src = hi ? wo_r : wo_i; }
        short4v v;
        #pragma unroll
        for (int j = 0; j < 4; ++j)
            v[j] = (short)bf16b(src[(long)(k2 + j) * 256 + col] * sgn);
        *(short4v*)(WoT + o) = v;
    }
}

// ---------------------------------------------------------------------------
// QKV projection GEMM. vT stored [bh][32 d][2048 n] with n's bits 2<->3
// SWAPPED inside each 32-key group (PV B-frag permutation pre-applied).
// ---------------------------------------------------------------------------
__global__ __launch_bounds__(256, 2) void gemm_proj(
    const float* __restrict__ xr_g, const float* __restrict__ xi_g,
    const u16* __restrict__ BT,
    u16* __restrict__ qr, u16* __restrict__ qi, u16* __restrict__ kr,
    u16* __restrict__ ki, u16* __restrict__ vrT, u16* __restrict__ viT)
{
    __shared__ __align__(16) u16 sA[128 * 32];
    __shared__ __align__(16) u16 sB[128 * 32];
    const int tid = threadIdx.x;
    const int lane = tid & 63, l31 = lane & 31, lh = lane >> 5;
    const int w = tid >> 6, wrow = w & 1, wcol = w >> 1;
    const int srow = tid >> 2, sseg = tid & 3;
    const int n0 = blockIdx.x * 128, m0 = blockIdx.y * 128;

    floatx16 a00 = {0}, a01 = {0}, a10 = {0}, a11 = {0};

    for (int kt = 0; kt < 512; kt += 32) {
        __syncthreads();
        const float* xbase = (kt < 256) ? xr_g : xi_g;
        const int kc = (kt & 255) + sseg * 8;
        #pragma unroll
        for (int i = 0; i < 2; ++i) {
            const int r = srow + i * 64;
            {
                const float* src = xbase + (long)(m0 + r) * 256 + kc;
                const float4 f0 = *(const float4*)(src);
                const float4 f1 = *(const float4*)(src + 4);
                short8 v;
                v[0] = (short)bf16b(f0.x); v[1] = (short)bf16b(f0.y);
                v[2] = (short)bf16b(f0.z); v[3] = (short)bf16b(f0.w);
                v[4] = (short)bf16b(f1.x); v[5] = (short)bf16b(f1.y);
                v[6] = (short)bf16b(f1.z); v[7] = (short)bf16b(f1.w);
                *(short8*)(sA + r * 32 + sseg * 8) = v;
            }
            *(short8*)(sB + r * 32 + sseg * 8) =
                *(const short8*)(BT + (long)(n0 + r) * 512 + kt + sseg * 8);
        }
        __syncthreads();
        #pragma unroll
        for (int s = 0; s < 2; ++s) {
            const int ko = s * 16 + lh * 8;
            const short8 fa0 = *(const short8*)(sA + (wrow * 64 + l31) * 32 + ko);
            const short8 fa1 = *(const short8*)(sA + (wrow * 64 + 32 + l31) * 32 + ko);
            const short8 fb0 = *(const short8*)(sB + (wcol * 64 + l31) * 32 + ko);
            const short8 fb1 = *(const short8*)(sB + (wcol * 64 + 32 + l31) * 32 + ko);
            a00 = MFMA_BF16(fa0, fb0, a00);
            a01 = MFMA_BF16(fa0, fb1, a01);
            a10 = MFMA_BF16(fa1, fb0, a10);
            a11 = MFMA_BF16(fa1, fb1, a11);
        }
    }

    floatx16 accs[2][2] = {{a00, a01}, {a10, a11}};
    #pragma unroll
    for (int rt = 0; rt < 2; ++rt) {
        #pragma unroll
        for (int ct = 0; ct < 2; ++ct) {
            const int colb = n0 + wcol * 64 + ct * 32;
            const int g = colb >> 8;
            const int h = (colb & 255) >> 5;
            if (g < 4) {
                u16* pl = (g == 0) ? qr : (g == 1) ? qi : (g == 2) ? kr : ki;
                #pragma unroll
                for (int reg = 0; reg < 16; ++reg) {
                    const int row = m0 + wrow * 64 + rt * 32 + (reg & 3) + 8 * (reg >> 2) + 4 * lh;
                    const int b = row >> 11, nn = row & 2047;
                    pl[(((long)(b * 8 + h)) * 2048 + nn) * 32 + l31] = bf16b(accs[rt][ct][reg]);
                }
            } else {
                u16* pl = (g == 4) ? vrT : viT;
                #pragma unroll
                for (int reg = 0; reg < 16; ++reg) {
                    const int row = m0 + wrow * 64 + rt * 32 + (reg & 3) + 8 * (reg >> 2) + 4 * lh;
                    const int b = row >> 11, nn = row & 2047;
                    // pre-apply PV permutation: swap bits 2<->3 of n
                    const int np = (nn & ~12) | ((nn & 4) << 1) | ((nn & 8) >> 1);
                    pl[(((long)(b * 8 + h)) * 32 + l31) * 2048 + np] = bf16b(accs[rt][ct][reg]);
                }
            }
        }
    }
}

// ---------------------------------------------------------------------------
// MFMA flash attention v7: R2 replica-wave skeleton with the per-tile
// critical path cut three ways:
//  1. K fragments live in REGISTERS, loaded coalesced straight from global
//     (wave's own ktype plane only; prefetched a full tile ahead). No K LDS
//     round-trip -> S-MFMAs issue immediately after the barrier.
//  2. V stays LDS-staged (shared by all 4 waves) but its 4 frag reads are
//     issued at barrier+0 so their latency hides under S-MFMA + exp.
//  3. Softmax denominator via ones-A MFMA into the idle matrix pipe
//     (all C rows equal -> no per-tile add chain, no final shfl).
// LDS: 10 KiB V double-buffer (16 KiB alloc for epilogue merge overlay).
// ---------------------------------------------------------------------------
__global__ __launch_bounds__(256, 4) void attn_kernel(
    const u16* __restrict__ qr_g, const u16* __restrict__ qi_g,
    const u16* __restrict__ kr_g, const u16* __restrict__ ki_g,
    const u16* __restrict__ vrT_g, const u16* __restrict__ viT_g,
    u16* __restrict__ xo)
{
    __shared__ __align__(16) u16 smem[8192];   // 16 KiB: 2x2560 V bufs | merge scratch

    const int tid = threadIdx.x;
    const int lane = tid & 63, l31 = lane & 31, lh = lane >> 5;
    const int w = tid >> 6, ktype = w & 1, qtype = w >> 1;
    const int bh = blockIdx.x;          // bh = blockIdx.x: fixed bh->XCD map
    const int i0 = blockIdx.y * 32;
    const long base = (long)bh * kN * kDH;

    // Q B-frags (lane = query column l31, k = d)
    const u16* qg = (qtype ? qi_g : qr_g) + base;
    short8 qB0, qB1;
    {
        const u16* qp = qg + (long)(i0 + l31) * kDH;
        qB0 = *(const short8*)(qp + lh * 8);
        qB1 = *(const short8*)(qp + 16 + lh * 8);
    }

    // V staging role: one b128 per thread per tile
    const int srow = tid & 63;   // vcol row: vr d 0..31, vi d 32..63
    const int sseg = tid >> 6;   // 8-elem segment
    const u16* vptr = ((srow < 32) ? vrT_g : viT_g)
                    + ((long)bh * 32 + (srow & 31)) * kN + sseg * 8;
    short8 vreg = *(const short8*)vptr;

    // K A-frags direct from global (wave's own ktype plane).
    // layout [bh][n][32d]: frag elems = K[key=t*32+l31][d = (a?16:0)+lh*8 ..+8]
    const u16* kAp = (ktype ? ki_g : kr_g) + base + (long)l31 * kDH + lh * 8;
    short8 ka0 = *(const short8*)(kAp);
    short8 ka1 = *(const short8*)(kAp + 16);

    const short8 ones8 = {(short)0x3F80, (short)0x3F80, (short)0x3F80, (short)0x3F80,
                          (short)0x3F80, (short)0x3F80, (short)0x3F80, (short)0x3F80};

    floatx16 Ur = {0}, Ui = {0}, Lacc = {0};

    for (int t = 0; t < 64; ++t) {
        u16* bV = smem + (t & 1) * 2560;
        *(short8*)(bV + srow * 40 + sseg * 8) = vreg;
        __syncthreads();
        if (t < 63) {
            // vT layout [d][n]: one 32-key tile = 32 elems along n
            vreg = *(const short8*)(vptr + (t + 1) * 32);
        }

        // V^T A-frags issued at barrier+0 (latency hides under S + exp)
        const short8 va0 = *(const short8*)(bV + l31 * 40 + lh * 8);
        const short8 va1 = *(const short8*)(bV + l31 * 40 + 16 + lh * 8);
        const short8 vb0 = *(const short8*)(bV + (32 + l31) * 40 + lh * 8);
        const short8 vb1 = *(const short8*)(bV + (32 + l31) * 40 + 16 + lh * 8);

        // S^T for this wave's replica: A = K rows (in regs), B = Q
        floatx16 S = {0};
        S = MFMA_BF16(ka0, qB0, S);
        S = MFMA_BF16(ka1, qB1, S);
        if (t < 63) {
            // prefetch next tile's K frags (consumed after next barrier)
            const long ko = (long)(t + 1) * 1024;
            ka0 = *(const short8*)(kAp + ko);
            ka1 = *(const short8*)(kAp + ko + 16);
        }

        // fused exp2 + bf16 pack (PV permutation pre-applied in V layout)
        const short8 Fa = mk8exp(S, 0);
        const short8 Fb = mk8exp(S, 8);

        // denominator: ones-A MFMA -> every C row = sum_k P[k][q]
        Lacc = MFMA_BF16(ones8, Fa, Lacc);
        Lacc = MFMA_BF16(ones8, Fb, Lacc);

        Ur = MFMA_BF16(va0, Fa, Ur);
        Ur = MFMA_BF16(va1, Fb, Ur);
        Ui = MFMA_BF16(vb0, Fa, Ui);
        Ui = MFMA_BF16(vb1, Fb, Ui);
    }

    const float iL = 1.f / Lacc[0];

    // per-replica signed contribution to (o_r, o_i):
    //   w0 (qr,kr): cr=+Ur, ci=+Ui
    //   w1 (qr,ki): cr=-Ui, ci=+Ur
    //   w2 (qi,kr): cr=-Ui, ci=+Ur
    //   w3 (qi,ki): cr=-Ur, ci=-Ui
    float cr[16], ci[16];
    #pragma unroll
    for (int r = 0; r < 16; ++r) {
        if (w == 0)      { cr[r] =  Ur[r] * iL; ci[r] =  Ui[r] * iL; }
        else if (w == 3) { cr[r] = -Ur[r] * iL; ci[r] = -Ui[r] * iL; }
        else             { cr[r] = -Ui[r] * iL; ci[r] =  Ur[r] * iL; }
    }

    // 3-phase replica merge in LDS (raw per-lane linear layout; all waves
    // share the same (lane,reg)->(query,d) C-mapping so reg-to-reg add is
    // exact). slot s = 2048 floats at sC + s*2048.
    __syncthreads();   // done with V buffers; overlay combine scratch
    float* sC = (float*)smem;
    if (qtype == 1) {                      // w2 -> slot0, w3 -> slot1
        float* dst = sC + ktype * 2048;
        #pragma unroll
        for (int r = 0; r < 16; ++r) {
            dst[r * 64 + lane] = cr[r];
            dst[1024 + r * 64 + lane] = ci[r];
        }
    }
    __syncthreads();
    if (qtype == 0) {
        float* s = sC + ktype * 2048;      // w0 reads slot0, w1 reads slot1
        #pragma unroll
        for (int r = 0; r < 16; ++r) {
            cr[r] += s[r * 64 + lane];
            ci[r] += s[1024 + r * 64 + lane];
        }
        if (ktype == 1) {                  // w1 re-dumps merged into slot1
            #pragma unroll
            for (int r = 0; r < 16; ++r) {
                s[r * 64 + lane] = cr[r];
                s[1024 + r * 64 + lane] = ci[r];
            }
        }
    }
    __syncthreads();
    if (w == 0) {
        const float* s = sC + 2048;
        #pragma unroll
        for (int r = 0; r < 16; ++r) {
            cr[r] += s[r * 64 + lane];
            ci[r] += s[1024 + r * 64 + lane];
        }
        const int b = bh >> 3, h = bh & 7;
        u16* xrow = xo + ((long)(b * 2048 + i0 + l31)) * 512 + h * 32;
        #pragma unroll
        for (int g = 0; g < 4; ++g) {
            const int d0 = 8 * g + 4 * lh;
            union { unsigned u[2]; uint2 v; } pr, pi;
            pr.u[0] = pack2(cr[4 * g + 0], cr[4 * g + 1]);
            pr.u[1] = pack2(cr[4 * g + 2], cr[4 * g + 3]);
            pi.u[0] = pack2(ci[4 * g + 0], ci[4 * g + 1]);
            pi.u[1] = pack2(ci[4 * g + 2], ci[4 * g + 3]);
            *(uint2*)(xrow + d0) = pr.v;
            *(uint2*)(xrow + 256 + d0) = pi.v;
        }
    }
}

// ---------------------------------------------------------------------------
// Output projection GEMM (unchanged).
// ---------------------------------------------------------------------------
__global__ __launch_bounds__(256, 2) void gemm_oproj(
    const u16* __restrict__ Xo, const u16* __restrict__ BT, float* __restrict__ out)
{
    __shared__ __align__(16) u16 sA[128 * 32];
    __shared__ __align__(16) u16 sB[128 * 32];
    const int tid = threadIdx.x;
    const int lane = tid & 63, l31 = lane & 31, lh = lane >> 5;
    const int w = tid >> 6, wrow = w & 1, wcol = w >> 1;
    const int srow = tid >> 2, sseg = tid & 3;
    const int n0 = blockIdx.x * 128, m0 = blockIdx.y * 128;

    floatx16 a00 = {0}, a01 = {0}, a10 = {0}, a11 = {0};

    for (int kt = 0; kt < 512; kt += 32) {
        __syncthreads();
        #pragma unroll
        for (int i = 0; i < 2; ++i) {
            const int r = srow + i * 64;
            *(short8*)(sA + r * 32 + sseg * 8) =
                *(const short8*)(Xo + (long)(m0 + r) * 512 + kt + sseg * 8);
            *(short8*)(sB + r * 32 + sseg * 8) =
                *(const short8*)(BT + (long)(n0 + r) * 512 + kt + sseg * 8);
        }
        __syncthreads();
        #pragma unroll
        for (int s = 0; s < 2; ++s) {
            const int ko = s * 16 + lh * 8;
            const short8 fa0 = *(const short8*)(sA + (wrow * 64 + l31) * 32 + ko);
            const short8 fa1 = *(const short8*)(sA + (wrow * 64 + 32 + l31) * 32 + ko);
            const short8 fb0 = *(const short8*)(sB + (wcol * 64 + l31) * 32 + ko);
            const short8 fb1 = *(const short8*)(sB + (wcol * 64 + 32 + l31) * 32 + ko);
            a00 = MFMA_BF16(fa0, fb0, a00);
            a01 = MFMA_BF16(fa0, fb1, a01);
            a10 = MFMA_BF16(fa1, fb0, a10);
            a11 = MFMA_BF16(fa1, fb1, a11);
        }
    }

    floatx16 accs[2][2] = {{a00, a01}, {a10, a11}};
    #pragma unroll
    for (int rt = 0; rt < 2; ++rt) {
        #pragma unroll
        for (int ct = 0; ct < 2; ++ct) {
            const int colb = n0 + wcol * 64 + ct * 32;
            #pragma unroll
            for (int reg = 0; reg < 16; ++reg) {
                const int row = m0 + wrow * 64 + rt * 32 + (reg & 3) + 8 * (reg >> 2) + 4 * lh;
                const int col = colb + l31;
                const float val = accs[rt][ct][reg];
                if (colb < 256) out[(long)row * 512 + col * 2] = val;
                else            out[(long)row * 512 + (col - 256) * 2 + 1] = val;
            }
        }
    }
}

extern "C" void kernel_launch(void* const* d_in, const int* in_sizes, int n_in,
                              void* d_out, int out_size, void* d_ws, size_t ws_size,
                              hipStream_t stream) {
    const float* xr    = (const float*)d_in[0];
    const float* xi    = (const float*)d_in[1];
    const float* wq_r  = (const float*)d_in[2];
    const float* wq_i  = (const float*)d_in[3];
    const float* wkv_r = (const float*)d_in[4];
    const float* wkv_i = (const float*)d_in[5];
    const float* wo_r  = (const float*)d_in[6];
    const float* wo_i  = (const float*)d_in[7];
    float* out = (float*)d_out;

    u16* ws16 = (u16*)d_ws;
    u16* qr   = ws16 + 0 * kPlane;
    u16* qi   = ws16 + 1 * kPlane;
    u16* kr   = ws16 + 2 * kPlane;
    u16* ki   = ws16 + 3 * kPlane;
    u16* vrT  = ws16 + 4 * kPlane;
    u16* viT  = ws16 + 5 * kPlane;
    u16* xo   = ws16 + 6 * kPlane;               // 2,097,152 elems
    u16* Wbig = ws16 + 8 * kPlane;               // 786,432 elems
    u16* WoT  = Wbig + 786432;                   // 262,144 elems

    prep_w<<<1024, 256, 0, stream>>>(wq_r, wq_i, wkv_r, wkv_i, wo_r, wo_i, Wbig, WoT);
    gemm_proj<<<dim3(12, 32), 256, 0, stream>>>(xr, xi, Wbig, qr, qi, kr, ki, vrT, viT);
    attn_kernel<<<dim3(kBH, kN / 32), 256, 0, stream>>>(qr, qi, kr, ki, vrT, viT, xo);
    gemm_oproj<<<dim3(4, 32), 256, 0, stream>>>(xo, WoT, out);
}

// Round 4
// 184.638 us; speedup vs baseline: 1.0093x; 1.0093x over previous
//
#include <hip/hip_runtime.h>
#include <math.h>

namespace {
constexpr int kB = 2, kN = 2048, kDim = 256, kH = 8, kDH = 32;
constexpr int kBH = kB * kH;
constexpr long kPlane = (long)kBH * kN * kDH;  // 1,048,576 elems per tensor
// DH^-0.5 / ln2 folded into stored q so softmax weight = exp2(score)
constexpr float kQScaleL2 = 0.25506852552f;
}

typedef unsigned short u16;
typedef short short8 __attribute__((ext_vector_type(8)));
typedef short short4v __attribute__((ext_vector_type(4)));
typedef float floatx16 __attribute__((ext_vector_type(16)));
#define MFMA_BF16(a, b, c) __builtin_amdgcn_mfma_f32_32x32x16_bf16(a, b, c, 0, 0, 0)

__device__ inline u16 bf16b(float x) {
    union { float f; unsigned u; } c; c.f = x;
    unsigned r = c.u + 0x7FFFu + ((c.u >> 16) & 1u);
    return (u16)(r >> 16);
}
__device__ inline unsigned pack2(float x, float y) {
    return (unsigned)bf16b(x) | ((unsigned)bf16b(y) << 16);
}
// truncating bf16 pack of two positive floats via one v_perm_b32
__device__ inline unsigned packtr(float lo, float hi) {
    return __builtin_amdgcn_perm(__float_as_uint(hi), __float_as_uint(lo), 0x07060302u);
}
__device__ inline short8 mk8(const float* e) {
    union { unsigned u[4]; short8 s; } c;
    c.u[0] = packtr(e[0], e[1]);
    c.u[1] = packtr(e[2], e[3]);
    c.u[2] = packtr(e[4], e[5]);
    c.u[3] = packtr(e[6], e[7]);
    return c.s;
}

// ---------------------------------------------------------------------------
// Build doubled/transposed bf16 weight matrices (unchanged).
// ---------------------------------------------------------------------------
__global__ __launch_bounds__(256, 2) void prep_w(
    const float* __restrict__ wq_r, const float* __restrict__ wq_i,
    const float* __restrict__ wkv_r, const float* __restrict__ wkv_i,
    const float* __restrict__ wo_r, const float* __restrict__ wo_i,
    u16* __restrict__ Wbig, u16* __restrict__ WoT)
{
    const long base = ((long)blockIdx.x * 256 + threadIdx.x) * 4;
    if (base < 786432) {
        const int c = (int)(base >> 9);
        const int k = (int)(base & 511);
        const int g = c >> 8, d = c & 255;
        const bool hi = k >= 256;
        const int k2 = hi ? k - 256 : k;
        const float* src;
        float sgn = 1.f;
        int col, stride;
        if (g < 2) {
            stride = 256; col = d;
            if (g == 0) { src = hi ? wq_i : wq_r; if (hi) sgn = -1.f; }
        else        { src = hi ? wq_r : wq_i; }
            sgn *= kQScaleL2;
        } else {
            stride = 512;
            col = (g >= 4) ? d + 256 : d;
            if ((g & 1) == 0) { src = hi ? wkv_i : wkv_r; if (hi) sgn = -1.f; }
            else              { src = hi ? wkv_r : wkv_i; }
        }
        short4v v;
        #pragma unroll
        for (int j = 0; j < 4; ++j)
            v[j] = (short)bf16b(src[(long)(k2 + j) * stride + col] * sgn);
        *(short4v*)(Wbig + base) = v;
    } else {
        const long o = base - 786432;
        const int c = (int)(o >> 9);
        const int k = (int)(o & 511);
        const bool hi = k >= 256;
        const int k2 = hi ? k - 256 : k;
        const float* src;
        float sgn = 1.f;
        int col;
        if (c < 256) { col = c;       src = hi ? wo_i : wo_r; if (hi) sgn = -1.f; }
        else         { col = c - 256; src = hi ? wo_r : wo_i; }
        short4v v;
        #pragma unroll
        for (int j = 0; j < 4; ++j)
            v[j] = (short)bf16b(src[(long)(k2 + j) * 256 + col] * sgn);
        *(short4v*)(WoT + o) = v;
    }
}

// ---------------------------------------------------------------------------
// QKV projection GEMM. vT stored [bh][32 d][2048 n] with n's bits 2<->3
// SWAPPED inside each 32-key group (PV B-frag permutation pre-applied).
// ---------------------------------------------------------------------------
__global__ __launch_bounds__(256, 2) void gemm_proj(
    const float* __restrict__ xr_g, const float* __restrict__ xi_g,
    const u16* __restrict__ BT,
    u16* __restrict__ qr, u16* __restrict__ qi, u16* __restrict__ kr,
    u16* __restrict__ ki, u16* __restrict__ vrT, u16* __restrict__ viT)
{
    __shared__ __align__(16) u16 sA[128 * 32];
    __shared__ __align__(16) u16 sB[128 * 32];
    const int tid = threadIdx.x;
    const int lane = tid & 63, l31 = lane & 31, lh = lane >> 5;
    const int w = tid >> 6, wrow = w & 1, wcol = w >> 1;
    const int srow = tid >> 2, sseg = tid & 3;
    const int n0 = blockIdx.x * 128, m0 = blockIdx.y * 128;

    floatx16 a00 = {0}, a01 = {0}, a10 = {0}, a11 = {0};

    for (int kt = 0; kt < 512; kt += 32) {
        __syncthreads();
        const float* xbase = (kt < 256) ? xr_g : xi_g;
        const int kc = (kt & 255) + sseg * 8;
        #pragma unroll
        for (int i = 0; i < 2; ++i) {
            const int r = srow + i * 64;
            {
                const float* src = xbase + (long)(m0 + r) * 256 + kc;
                const float4 f0 = *(const float4*)(src);
                const float4 f1 = *(const float4*)(src + 4);
                short8 v;
                v[0] = (short)bf16b(f0.x); v[1] = (short)bf16b(f0.y);
                v[2] = (short)bf16b(f0.z); v[3] = (short)bf16b(f0.w);
                v[4] = (short)bf16b(f1.x); v[5] = (short)bf16b(f1.y);
                v[6] = (short)bf16b(f1.z); v[7] = (short)bf16b(f1.w);
                *(short8*)(sA + r * 32 + sseg * 8) = v;
            }
            *(short8*)(sB + r * 32 + sseg * 8) =
                *(const short8*)(BT + (long)(n0 + r) * 512 + kt + sseg * 8);
        }
        __syncthreads();
        #pragma unroll
        for (int s = 0; s < 2; ++s) {
            const int ko = s * 16 + lh * 8;
            const short8 fa0 = *(const short8*)(sA + (wrow * 64 + l31) * 32 + ko);
            const short8 fa1 = *(const short8*)(sA + (wrow * 64 + 32 + l31) * 32 + ko);
            const short8 fb0 = *(const short8*)(sB + (wcol * 64 + l31) * 32 + ko);
            const short8 fb1 = *(const short8*)(sB + (wcol * 64 + 32 + l31) * 32 + ko);
            a00 = MFMA_BF16(fa0, fb0, a00);
            a01 = MFMA_BF16(fa0, fb1, a01);
            a10 = MFMA_BF16(fa1, fb0, a10);
            a11 = MFMA_BF16(fa1, fb1, a11);
        }
    }

    floatx16 accs[2][2] = {{a00, a01}, {a10, a11}};
    #pragma unroll
    for (int rt = 0; rt < 2; ++rt) {
        #pragma unroll
        for (int ct = 0; ct < 2; ++ct) {
            const int colb = n0 + wcol * 64 + ct * 32;
            const int g = colb >> 8;
            const int h = (colb & 255) >> 5;
            if (g < 4) {
                u16* pl = (g == 0) ? qr : (g == 1) ? qi : (g == 2) ? kr : ki;
                #pragma unroll
                for (int reg = 0; reg < 16; ++reg) {
                    const int row = m0 + wrow * 64 + rt * 32 + (reg & 3) + 8 * (reg >> 2) + 4 * lh;
                    const int b = row >> 11, nn = row & 2047;
                    pl[(((long)(b * 8 + h)) * 2048 + nn) * 32 + l31] = bf16b(accs[rt][ct][reg]);
                }
            } else {
                u16* pl = (g == 4) ? vrT : viT;
                #pragma unroll
                for (int reg = 0; reg < 16; ++reg) {
                    const int row = m0 + wrow * 64 + rt * 32 + (reg & 3) + 8 * (reg >> 2) + 4 * lh;
                    const int b = row >> 11, nn = row & 2047;
                    // pre-apply PV permutation: swap bits 2<->3 of n
                    const int np = (nn & ~12) | ((nn & 4) << 1) | ((nn & 8) >> 1);
                    pl[(((long)(b * 8 + h)) * 32 + l31) * 2048 + np] = bf16b(accs[rt][ct][reg]);
                }
            }
        }
    }
}

// ---------------------------------------------------------------------------
// MFMA flash attention v8: replica-wave skeleton + S-pipelining.
//  - K frags in REGISTERS from global, prefetched 2 tiles ahead (vmcnt cover
//    = a full iteration). S(t+1) is computed DURING iteration t: it has no
//    LDS/barrier dependency, so its matrix-pipe work overlaps exp2 (trans
//    pipe) and PV. Per-iteration chain: exp(S_prev) -> pack -> PV (~350 cyc
//    vs 540 in the lockstep version).
//  - V stays LDS-staged (shared by all 4 waves; 4x amortization).
//  - Denominator on VALU with 4 partial accumulators (no serial chain; the
//    R3 ones-MFMA cost more matrix time than it saved in VALU).
//  - Co-resident blocks time-staggered via s_sleep so the 4 waves/SIMD stop
//    phase-aligning; setprio(1) around PV keeps the matrix pipe fed.
// ---------------------------------------------------------------------------
__global__ __launch_bounds__(256, 4) void attn_kernel(
    const u16* __restrict__ qr_g, const u16* __restrict__ qi_g,
    const u16* __restrict__ kr_g, const u16* __restrict__ ki_g,
    const u16* __restrict__ vrT_g, const u16* __restrict__ viT_g,
    u16* __restrict__ xo)
{
    __shared__ __align__(16) u16 smem[8192];   // 16 KiB: 2x2560 V bufs | merge scratch

    const int tid = threadIdx.x;
    const int lane = tid & 63, l31 = lane & 31, lh = lane >> 5;
    const int w = tid >> 6, ktype = w & 1, qtype = w >> 1;
    const int bh = blockIdx.x;          // bh = blockIdx.x: fixed bh->XCD map
    const int i0 = blockIdx.y * 32;
    const long base = (long)bh * kN * kDH;

    // time-stagger co-resident blocks (same dispatch round = same CU cohort)
    {
        const int rnd = ((blockIdx.x + 16 * blockIdx.y) >> 8) & 3;
        switch (rnd) {
            case 1: __builtin_amdgcn_s_sleep(2); break;   // ~128 cyc
            case 2: __builtin_amdgcn_s_sleep(4); break;   // ~256 cyc
            case 3: __builtin_amdgcn_s_sleep(6); break;   // ~384 cyc
            default: break;
        }
    }

    // Q B-frags (lane = query column l31, k = d)
    const u16* qg = (qtype ? qi_g : qr_g) + base;
    short8 qB0, qB1;
    {
        const u16* qp = qg + (long)(i0 + l31) * kDH;
        qB0 = *(const short8*)(qp + lh * 8);
        qB1 = *(const short8*)(qp + 16 + lh * 8);
    }

    // V staging role: one b128 per thread per tile
    const int srow = tid & 63;   // vcol row: vr d 0..31, vi d 32..63
    const int sseg = tid >> 6;   // 8-elem segment
    const u16* vptr = ((srow < 32) ? vrT_g : viT_g)
                    + ((long)bh * 32 + (srow & 31)) * kN + sseg * 8;
    short8 vreg = *(const short8*)vptr;

    // K A-frags direct from global (wave's own ktype plane).
    // layout [bh][n][32d]: frag elems = K[key=t*32+l31][d = (a?16:0)+lh*8 ..+8]
    const u16* kAp = (ktype ? ki_g : kr_g) + base + (long)l31 * kDH + lh * 8;
    short8 ka0 = *(const short8*)(kAp);
    short8 ka1 = *(const short8*)(kAp + 16);
    short8 kn0 = *(const short8*)(kAp + 1024);
    short8 kn1 = *(const short8*)(kAp + 1024 + 16);

    floatx16 Ur = {0}, Ui = {0};
    float La0 = 0.f, La1 = 0.f, La2 = 0.f, La3 = 0.f;

    // prologue: S for tile 0; then ka <- K(1)
    floatx16 S = {0};
    S = MFMA_BF16(ka0, qB0, S);
    S = MFMA_BF16(ka1, qB1, S);
    ka0 = kn0; ka1 = kn1;

    for (int t = 0; t < 64; ++t) {
        u16* bV = smem + (t & 1) * 2560;
        *(short8*)(bV + srow * 40 + sseg * 8) = vreg;
        __syncthreads();
        if (t < 63) {
            // vT layout [d][n]: one 32-key tile = 32 elems along n
            vreg = *(const short8*)(vptr + (t + 1) * 32);
        }
        if (t < 62) {
            // K(t+2): consumed by the S-pipeline at iteration t+1
            kn0 = *(const short8*)(kAp + (long)(t + 2) * 1024);
            kn1 = *(const short8*)(kAp + (long)(t + 2) * 1024 + 16);
        }

        // V^T A-frags at barrier+0: latency hides under exp of S_prev
        const short8 va0 = *(const short8*)(bV + l31 * 40 + lh * 8);
        const short8 va1 = *(const short8*)(bV + l31 * 40 + 16 + lh * 8);
        const short8 vb0 = *(const short8*)(bV + (32 + l31) * 40 + lh * 8);
        const short8 vb1 = *(const short8*)(bV + (32 + l31) * 40 + 16 + lh * 8);

        // softmax weights for THIS tile from the pipelined S
        float e[16];
        #pragma unroll
        for (int r = 0; r < 16; ++r) e[r] = __builtin_amdgcn_exp2f(S[r]);
        #pragma unroll
        for (int r = 0; r < 16; r += 4) {
            La0 += e[r + 0]; La1 += e[r + 1];
            La2 += e[r + 2]; La3 += e[r + 3];
        }
        const short8 Fa = mk8(&e[0]);
        const short8 Fb = mk8(&e[8]);

        // next tile's S: register-only MFMAs, no LDS/barrier dependency --
        // overlaps this tile's exp (trans pipe) and PV on the matrix pipe
        floatx16 Sn = {0};
        if (t < 63) {
            Sn = MFMA_BF16(ka0, qB0, Sn);
            Sn = MFMA_BF16(ka1, qB1, Sn);
        }

        __builtin_amdgcn_s_setprio(1);
        Ur = MFMA_BF16(va0, Fa, Ur);
        Ur = MFMA_BF16(va1, Fb, Ur);
        Ui = MFMA_BF16(vb0, Fa, Ui);
        Ui = MFMA_BF16(vb1, Fb, Ui);
        __builtin_amdgcn_s_setprio(0);

        S = Sn;
        ka0 = kn0; ka1 = kn1;
    }

    float La = (La0 + La1) + (La2 + La3);
    La += __shfl_xor(La, 32);
    const float iL = 1.f / La;

    // per-replica signed contribution to (o_r, o_i):
    //   w0 (qr,kr): cr=+Ur, ci=+Ui
    //   w1 (qr,ki): cr=-Ui, ci=+Ur
    //   w2 (qi,kr): cr=-Ui, ci=+Ur
    //   w3 (qi,ki): cr=-Ur, ci=-Ui
    float cr[16], ci[16];
    #pragma unroll
    for (int r = 0; r < 16; ++r) {
        if (w == 0)      { cr[r] =  Ur[r] * iL; ci[r] =  Ui[r] * iL; }
        else if (w == 3) { cr[r] = -Ur[r] * iL; ci[r] = -Ui[r] * iL; }
        else             { cr[r] = -Ui[r] * iL; ci[r] =  Ur[r] * iL; }
    }

    // 3-phase replica merge in LDS (raw per-lane linear layout; all waves
    // share the same (lane,reg)->(query,d) C-mapping so reg-to-reg add is
    // exact). slot s = 2048 floats at sC + s*2048.
    __syncthreads();   // done with V buffers; overlay combine scratch
    float* sC = (float*)smem;
    if (qtype == 1) {                      // w2 -> slot0, w3 -> slot1
        float* dst = sC + ktype * 2048;
        #pragma unroll
        for (int r = 0; r < 16; ++r) {
            dst[r * 64 + lane] = cr[r];
            dst[1024 + r * 64 + lane] = ci[r];
        }
    }
    __syncthreads();
    if (qtype == 0) {
        float* s = sC + ktype * 2048;      // w0 reads slot0, w1 reads slot1
        #pragma unroll
        for (int r = 0; r < 16; ++r) {
            cr[r] += s[r * 64 + lane];
            ci[r] += s[1024 + r * 64 + lane];
        }
        if (ktype == 1) {                  // w1 re-dumps merged into slot1
            #pragma unroll
            for (int r = 0; r < 16; ++r) {
                s[r * 64 + lane] = cr[r];
                s[1024 + r * 64 + lane] = ci[r];
            }
        }
    }
    __syncthreads();
    if (w == 0) {
        const float* s = sC + 2048;
        #pragma unroll
        for (int r = 0; r < 16; ++r) {
            cr[r] += s[r * 64 + lane];
            ci[r] += s[1024 + r * 64 + lane];
        }
        const int b = bh >> 3, h = bh & 7;
        u16* xrow = xo + ((long)(b * 2048 + i0 + l31)) * 512 + h * 32;
        #pragma unroll
        for (int g = 0; g < 4; ++g) {
            const int d0 = 8 * g + 4 * lh;
            union { unsigned u[2]; uint2 v; } pr, pi;
            pr.u[0] = pack2(cr[4 * g + 0], cr[4 * g + 1]);
            pr.u[1] = pack2(cr[4 * g + 2], cr[4 * g + 3]);
            pi.u[0] = pack2(ci[4 * g + 0], ci[4 * g + 1]);
            pi.u[1] = pack2(ci[4 * g + 2], ci[4 * g + 3]);
            *(uint2*)(xrow + d0) = pr.v;
            *(uint2*)(xrow + 256 + d0) = pi.v;
        }
    }
}

// ---------------------------------------------------------------------------
// Output projection GEMM (unchanged).
// ---------------------------------------------------------------------------
__global__ __launch_bounds__(256, 2) void gemm_oproj(
    const u16* __restrict__ Xo, const u16* __restrict__ BT, float* __restrict__ out)
{
    __shared__ __align__(16) u16 sA[128 * 32];
    __shared__ __align__(16) u16 sB[128 * 32];
    const int tid = threadIdx.x;
    const int lane = tid & 63, l31 = lane & 31, lh = lane >> 5;
    const int w = tid >> 6, wrow = w & 1, wcol = w >> 1;
    const int srow = tid >> 2, sseg = tid & 3;
    const int n0 = blockIdx.x * 128, m0 = blockIdx.y * 128;

    floatx16 a00 = {0}, a01 = {0}, a10 = {0}, a11 = {0};

    for (int kt = 0; kt < 512; kt += 32) {
        __syncthreads();
        #pragma unroll
        for (int i = 0; i < 2; ++i) {
            const int r = srow + i * 64;
            *(short8*)(sA + r * 32 + sseg * 8) =
                *(const short8*)(Xo + (long)(m0 + r) * 512 + kt + sseg * 8);
            *(short8*)(sB + r * 32 + sseg * 8) =
                *(const short8*)(BT + (long)(n0 + r) * 512 + kt + sseg * 8);
        }
        __syncthreads();
        #pragma unroll
        for (int s = 0; s < 2; ++s) {
            const int ko = s * 16 + lh * 8;
            const short8 fa0 = *(const short8*)(sA + (wrow * 64 + l31) * 32 + ko);
            const short8 fa1 = *(const short8*)(sA + (wrow * 64 + 32 + l31) * 32 + ko);
            const short8 fb0 = *(const short8*)(sB + (wcol * 64 + l31) * 32 + ko);
            const short8 fb1 = *(const short8*)(sB + (wcol * 64 + 32 + l31) * 32 + ko);
            a00 = MFMA_BF16(fa0, fb0, a00);
            a01 = MFMA_BF16(fa0, fb1, a01);
            a10 = MFMA_BF16(fa1, fb0, a10);
            a11 = MFMA_BF16(fa1, fb1, a11);
        }
    }

    floatx16 accs[2][2] = {{a00, a01}, {a10, a11}};
    #pragma unroll
    for (int rt = 0; rt < 2; ++rt) {
        #pragma unroll
        for (int ct = 0; ct < 2; ++ct) {
            const int colb = n0 + wcol * 64 + ct * 32;
            #pragma unroll
            for (int reg = 0; reg < 16; ++reg) {
                const int row = m0 + wrow * 64 + rt * 32 + (reg & 3) + 8 * (reg >> 2) + 4 * lh;
                const int col = colb + l31;
                const float val = accs[rt][ct][reg];
                if (colb < 256) out[(long)row * 512 + col * 2] = val;
                else            out[(long)row * 512 + (col - 256) * 2 + 1] = val;
            }
        }
    }
}

extern "C" void kernel_launch(void* const* d_in, const int* in_sizes, int n_in,
                              void* d_out, int out_size, void* d_ws, size_t ws_size,
                              hipStream_t stream) {
    const float* xr    = (const float*)d_in[0];
    const float* xi    = (const float*)d_in[1];
    const float* wq_r  = (const float*)d_in[2];
    const float* wq_i  = (const float*)d_in[3];
    const float* wkv_r = (const float*)d_in[4];
    const float* wkv_i = (const float*)d_in[5];
    const float* wo_r  = (const float*)d_in[6];
    const float* wo_i  = (const float*)d_in[7];
    float* out = (float*)d_out;

    u16* ws16 = (u16*)d_ws;
    u16* qr   = ws16 + 0 * kPlane;
    u16* qi   = ws16 + 1 * kPlane;
    u16* kr   = ws16 + 2 * kPlane;
    u16* ki   = ws16 + 3 * kPlane;
    u16* vrT  = ws16 + 4 * kPlane;
    u16* viT  = ws16 + 5 * kPlane;
    u16* xo   = ws16 + 6 * kPlane;               // 2,097,152 elems
    u16* Wbig = ws16 + 8 * kPlane;               // 786,432 elems
    u16* WoT  = Wbig + 786432;                   // 262,144 elems

    prep_w<<<1024, 256, 0, stream>>>(wq_r, wq_i, wkv_r, wkv_i, wo_r, wo_i, Wbig, WoT);
    gemm_proj<<<dim3(12, 32), 256, 0, stream>>>(xr, xi, Wbig, qr, qi, kr, ki, vrT, viT);
    attn_kernel<<<dim3(kBH, kN / 32), 256, 0, stream>>>(qr, qi, kr, ki, vrT, viT, xo);
    gemm_oproj<<<dim3(4, 32), 256, 0, stream>>>(xo, WoT, out);
}